// Round 12
// baseline (52.031 us; speedup 1.0000x reference)
//
#include <hip/hip_runtime.h>

// QuantHotLowRank: out[n][d] = sum_r Uq[ids[n]][r] * Bq[r][d]
// K=200000, R=64, D=1024, N=16384, 4-bit groupwise fake-quant, group=32.
//
// Two kernels (ledger: coop grid-sync 5.7x worse R9; in-gemm B-requant +7us
// R11; BM=128 neutral R10 -> gemm is overlap-limited, not instruction-bound):
//   1) quantB: B [64,1024] -> split-bf16 Bq^T planes [1024][64] (hi,lo) in ws.
//   2) gemm:   ZERO-LDS, barrier-free dataflow. BqT is 256KB = L2-resident
//              on every XCD, so B fragments are read straight from global
//              (~768B/thread of L2 hits); A rows gathered + fp64-quantized
//              in-register; 24 MFMAs (hi*hi+hi*lo+lo*hi, exact ~2^-18);
//              direct per-fragment nt stores (measured neutral vs LDS
//              transpose in R3/R4). launch_bounds(256,8) targets VGPR<=64
//              -> 8 blocks/CU, 2x the TLP of the LDS version.
//
// Quant decisions in FP64 to bit-match the numpy-fp64 reference (fp32 flips
// levels at w/scale ~ n+.5 -> absmax 1.06; fp64 -> 0.25 = 1 bf16 ULP floor).

#define R_DIM 64
#define D_DIM 1024
#define N_IDS 16384

#define BM 64          // rows per tile (4 waves x 16)
#define BN 64          // cols per tile (4 n-frags)

typedef __attribute__((ext_vector_type(8))) __bf16 bf16x8;
typedef __attribute__((ext_vector_type(4))) float f32x4;

__device__ inline unsigned short f32_to_bf16_rne(float f) {
  union { float f; unsigned int u; } c; c.f = f;
  unsigned int u = c.u;
  u += 0x7fffu + ((u >> 16) & 1u);   // round-to-nearest-even (finite inputs only)
  return (unsigned short)(u >> 16);
}

__device__ inline float bf16_bits_to_f32(unsigned short h) {
  union { unsigned int u; float f; } c; c.u = ((unsigned int)h) << 16;
  return c.f;
}

// fp64 fake-quant of one element given the group's fp64 scale (= amax/7,
// hoisted -- identical bits to recomputing per element).
__device__ inline void quant_elem(float w, double scale,
                                  unsigned short* hi, unsigned short* lo) {
  double t = (double)w / scale;                    // exact IEEE fp64 div = np
  double q = fmin(fmax(rint(t), -7.0), 7.0) * scale;
  float qf = (float)q;
  unsigned short h = f32_to_bf16_rne(qf);
  *hi = h;
  *lo = f32_to_bf16_rne(qf - bf16_bits_to_f32(h));
}

// ---------------- Kernel 1: quantize B -> split Bq^T (bf16 hi/lo planes) ----
// 64 blocks x 256 threads x 4 elems (float4); group of 32 = 8 consecutive
// lanes' float4s (aligned since 256 % 8 == 0).
__global__ __launch_bounds__(256) void quantB_kernel(
    const float* __restrict__ B,
    unsigned short* __restrict__ BqT_hi, unsigned short* __restrict__ BqT_lo) {
  int e4 = blockIdx.x * 256 + threadIdx.x;   // 0..16383
  int e  = e4 * 4;
  int r  = e >> 10;                          // row in [0,64)
  int c  = e & 1023;                         // col in [0,1024), 4 consecutive
  float4 w = *(const float4*)(B + e);
  float a = fmaxf(fmaxf(fabsf(w.x), fabsf(w.y)), fmaxf(fabsf(w.z), fabsf(w.w)));
  a = fmaxf(a, __shfl_xor(a, 1));
  a = fmaxf(a, __shfl_xor(a, 2));
  a = fmaxf(a, __shfl_xor(a, 4));
  double sc = fmax((double)a, 1e-8) / 7.0;
  float wv[4] = {w.x, w.y, w.z, w.w};
  #pragma unroll
  for (int j = 0; j < 4; ++j) {
    unsigned short hi, lo;
    quant_elem(wv[j], sc, &hi, &lo);
    BqT_hi[(c + j) * R_DIM + r] = hi;
    BqT_lo[(c + j) * R_DIM + r] = lo;
  }
}

// ---------------- Kernel 2: zero-LDS barrier-free gather/quant/MFMA ---------
__global__ __launch_bounds__(256, 8) void gemm_kernel(
    const float* __restrict__ U, const int* __restrict__ ids,
    const unsigned short* __restrict__ BqT_hi, const unsigned short* __restrict__ BqT_lo,
    float* __restrict__ out) {
  const int tid  = threadIdx.x;
  const int lane = tid & 63;
  const int wave = tid >> 6;
  const int bx   = blockIdx.x;
  const int nb   = bx & 15;    // 16 col-slices; consecutive blocks share mb
  const int mb   = bx >> 4;    //  -> same U rows hit L3/L2 concurrently
  const int n0   = nb * BN;
  const int m0   = mb * BM + wave * 16;
  const int koff  = (lane >> 4) * 8;         // k-chunk of 8 within the 32-group
  const int nlane = lane & 15;

  // --- A gather (issue first; latency hides under the quant VALU work) -----
  const float* urow = U + (size_t)ids[m0 + nlane] * R_DIM;
  float4 wr[2][2];
  #pragma unroll
  for (int s = 0; s < 2; ++s) {
    wr[s][0] = *(const float4*)(urow + s * 32 + koff);
    wr[s][1] = *(const float4*)(urow + s * 32 + koff + 4);
  }

  // --- fp64-quantize A fragments in-register -------------------------------
  // Lane holds elems s*32+koff..+8 of its row; lanes {l&15 fixed, l>>4
  // varying} hold one 32-elem quant group -> amax via shfl_xor 16/32.
  bf16x8 ah[2], al[2];
  #pragma unroll
  for (int s = 0; s < 2; ++s) {
    float4 w0 = wr[s][0], w1 = wr[s][1];
    float wv[8] = {w0.x, w0.y, w0.z, w0.w, w1.x, w1.y, w1.z, w1.w};
    float a = 0.0f;
    #pragma unroll
    for (int j = 0; j < 8; ++j) a = fmaxf(a, fabsf(wv[j]));
    a = fmaxf(a, __shfl_xor(a, 16));
    a = fmaxf(a, __shfl_xor(a, 32));
    double sc = fmax((double)a, 1e-8) / 7.0;
    union { unsigned short s8[8]; bf16x8 b; } uh, ul;
    #pragma unroll
    for (int j = 0; j < 8; ++j) {
      unsigned short hi, lo;
      quant_elem(wv[j], sc, &hi, &lo);
      uh.s8[j] = hi;
      ul.s8[j] = lo;
    }
    ah[s] = uh.b;
    al[s] = ul.b;
  }

  // --- MFMA, B fragments straight from L2-resident BqT ---------------------
  // (nf,s): 64 lanes collectively read rows n0+nf*16..+16 = one contiguous
  // 2KB span per plane -- fully coalesced, L2-hot (BqT = 256KB total).
  f32x4 acc[4];
  #pragma unroll
  for (int nf = 0; nf < 4; ++nf) acc[nf] = (f32x4){0.f, 0.f, 0.f, 0.f};

  #pragma unroll
  for (int nf = 0; nf < 4; ++nf) {
    const size_t brow = (size_t)(n0 + nf * 16 + nlane) * R_DIM;
    #pragma unroll
    for (int s = 0; s < 2; ++s) {
      bf16x8 bh = *(const bf16x8*)&BqT_hi[brow + s * 32 + koff];
      bf16x8 bl = *(const bf16x8*)&BqT_lo[brow + s * 32 + koff];
      acc[nf] = __builtin_amdgcn_mfma_f32_16x16x32_bf16(ah[s], bh, acc[nf], 0, 0, 0);
      acc[nf] = __builtin_amdgcn_mfma_f32_16x16x32_bf16(ah[s], bl, acc[nf], 0, 0, 0);
      acc[nf] = __builtin_amdgcn_mfma_f32_16x16x32_bf16(al[s], bh, acc[nf], 0, 0, 0);
    }
  }

  // --- direct fragment stores: D[row=(l>>4)*4+i][col=l&15] (verified R1-R3) -
  const int orow0 = m0 + ((lane >> 4) << 2);
  #pragma unroll
  for (int nf = 0; nf < 4; ++nf) {
    const int ocol = n0 + nf * 16 + nlane;
    #pragma unroll
    for (int i = 0; i < 4; ++i) {
      __builtin_nontemporal_store(acc[nf][i],
          &out[(size_t)(orow0 + i) * D_DIM + ocol]);
    }
  }
}

extern "C" void kernel_launch(void* const* d_in, const int* in_sizes, int n_in,
                              void* d_out, int out_size, void* d_ws, size_t ws_size,
                              hipStream_t stream) {
  const float* U   = (const float*)d_in[0];
  const float* B   = (const float*)d_in[1];
  const int*   ids = (const int*)d_in[2];
  float* out = (float*)d_out;

  unsigned short* BqT_hi = (unsigned short*)d_ws;                       // 128 KB
  unsigned short* BqT_lo = BqT_hi + R_DIM * D_DIM;                      // 128 KB

  quantB_kernel<<<(R_DIM * D_DIM) / (256 * 4), 256, 0, stream>>>(B, BqT_hi, BqT_lo);
  gemm_kernel<<<(N_IDS / BM) * (D_DIM / BN), 256, 0, stream>>>(U, ids, BqT_hi, BqT_lo, out);
}

// Round 13
// 32.693 us; speedup vs baseline: 1.5915x; 1.5915x over previous
//
#include <hip/hip_runtime.h>

// QuantHotLowRank: out[n][d] = sum_r Uq[ids[n]][r] * Bq[r][d]
// K=200000, R=64, D=1024, N=16384, 4-bit groupwise fake-quant, group=32.
//
// Two kernels. Ledger: coop grid-sync 5.7x worse (R9); per-block B-requant
// +7us DP-VALU (R11); zero-LDS @ launch_bounds(256,8) -> VGPR=32 -> load-
// latency serialization, 52us (R12); BM=128 & nt-stores & LDS-transpose all
// neutral. Theory now: 4 blocks/CU phase-lockstep keeps the HBM store phase
// from saturating. This round: BN=64 -> LDS 18KB -> 8 blocks/CU, with LDS
// staging retained (so low VGPR doesn't starve the load queue like R12).
//   1) quantB: B [64,1024] -> split-bf16 Bq^T planes [1024][64] (hi,lo) in ws.
//   2) gemm:   64x64 tiles, 4096 blocks, 8/CU. A gather + fp64 in-register
//              quant; B slice from XCD-affine L2 (nb = bx&15, nb==bx mod 8)
//              into LDS; split-bf16 MFMA (hi*hi+hi*lo+lo*hi, ~2^-18);
//              LDS-transpose + coalesced 256B-segment nt stores.
//
// Quant decisions in FP64 to bit-match the numpy-fp64 reference (fp32 flips
// levels at w/scale ~ n+.5 -> absmax 1.06; fp64 -> 0.25 = 1 bf16 ULP floor).

#define R_DIM 64
#define D_DIM 1024
#define N_IDS 16384

#define BM 64          // rows per tile (4 waves x 16)
#define BN 64          // cols per tile (4 n-frags)
#define LDS_STRIDE 72  // ushorts per B-LDS row: 64 + 8 pad
#define OT_STRIDE 68   // floats per out-LDS row: 64 + 4 pad

typedef __attribute__((ext_vector_type(8))) __bf16 bf16x8;
typedef __attribute__((ext_vector_type(4))) float f32x4;

__device__ inline unsigned short f32_to_bf16_rne(float f) {
  union { float f; unsigned int u; } c; c.f = f;
  unsigned int u = c.u;
  u += 0x7fffu + ((u >> 16) & 1u);   // round-to-nearest-even (finite inputs only)
  return (unsigned short)(u >> 16);
}

__device__ inline float bf16_bits_to_f32(unsigned short h) {
  union { unsigned int u; float f; } c; c.u = ((unsigned int)h) << 16;
  return c.f;
}

// fp64 fake-quant of one element given the group's fp64 scale (= amax/7,
// hoisted -- identical bits to recomputing per element).
__device__ inline void quant_elem(float w, double scale,
                                  unsigned short* hi, unsigned short* lo) {
  double t = (double)w / scale;                    // exact IEEE fp64 div = np
  double q = fmin(fmax(rint(t), -7.0), 7.0) * scale;
  float qf = (float)q;
  unsigned short h = f32_to_bf16_rne(qf);
  *hi = h;
  *lo = f32_to_bf16_rne(qf - bf16_bits_to_f32(h));
}

// ---------------- Kernel 1: quantize B -> split Bq^T (bf16 hi/lo planes) ----
// 64 blocks x 256 threads x 4 elems (float4); group of 32 = 8 consecutive
// lanes' float4s (aligned since 256 % 8 == 0).
__global__ __launch_bounds__(256) void quantB_kernel(
    const float* __restrict__ B,
    unsigned short* __restrict__ BqT_hi, unsigned short* __restrict__ BqT_lo) {
  int e4 = blockIdx.x * 256 + threadIdx.x;   // 0..16383
  int e  = e4 * 4;
  int r  = e >> 10;                          // row in [0,64)
  int c  = e & 1023;                         // col in [0,1024), 4 consecutive
  float4 w = *(const float4*)(B + e);
  float a = fmaxf(fmaxf(fabsf(w.x), fabsf(w.y)), fmaxf(fabsf(w.z), fabsf(w.w)));
  a = fmaxf(a, __shfl_xor(a, 1));
  a = fmaxf(a, __shfl_xor(a, 2));
  a = fmaxf(a, __shfl_xor(a, 4));
  double sc = fmax((double)a, 1e-8) / 7.0;
  float wv[4] = {w.x, w.y, w.z, w.w};
  #pragma unroll
  for (int j = 0; j < 4; ++j) {
    unsigned short hi, lo;
    quant_elem(wv[j], sc, &hi, &lo);
    BqT_hi[(c + j) * R_DIM + r] = hi;
    BqT_lo[(c + j) * R_DIM + r] = lo;
  }
}

// ---------------- Kernel 2: 64x64 tile, 8 blocks/CU, LDS-staged MFMA --------
__global__ __launch_bounds__(256, 8) void gemm_kernel(
    const float* __restrict__ U, const int* __restrict__ ids,
    const unsigned short* __restrict__ BqT_hi, const unsigned short* __restrict__ BqT_lo,
    float* __restrict__ out) {
  // B planes (2 x 9KB) overlaid with the out-transpose buffer (17KB).
  // 18432B -> 8 blocks/CU.
  __shared__ char smem[2 * BN * LDS_STRIDE * 2];
  unsigned short* bt_hi = (unsigned short*)smem;
  unsigned short* bt_lo = bt_hi + BN * LDS_STRIDE;
  float* ot = (float*)smem;

  const int tid  = threadIdx.x;
  const int lane = tid & 63;
  const int wave = tid >> 6;
  const int bx   = blockIdx.x;
  const int nb   = bx & 15;    // 16 col-slices; nb == bx mod 8 -> fixed XCD:
  const int mb   = bx >> 4;    //  each XCD L2 serves 2 hot 16KB BqT slices
  const int n0   = nb * BN;
  const int m0   = mb * BM + wave * 16;
  const int koff  = (lane >> 4) * 8;         // k-chunk of 8 within the 32-group
  const int nlane = lane & 15;

  // --- A gather first (in flight under B staging + quant VALU) -------------
  const float* urow = U + (size_t)ids[m0 + nlane] * R_DIM;
  float4 wr[2][2];
  #pragma unroll
  for (int s = 0; s < 2; ++s) {
    wr[s][0] = *(const float4*)(urow + s * 32 + koff);
    wr[s][1] = *(const float4*)(urow + s * 32 + koff + 4);
  }

  // --- stage Bq^T slice (rows n0..n0+63 = one contiguous 8KB span/plane) ---
  {
    const uint4* src_hi = (const uint4*)(BqT_hi + (size_t)n0 * R_DIM);
    const uint4* src_lo = (const uint4*)(BqT_lo + (size_t)n0 * R_DIM);
    #pragma unroll
    for (int it = 0; it < 2; ++it) {
      int c = tid + it * 256;                // 16B chunk index, 0..511
      int row = c >> 3, off = c & 7;
      *(uint4*)&bt_hi[row * LDS_STRIDE + off * 8] = src_hi[c];
      *(uint4*)&bt_lo[row * LDS_STRIDE + off * 8] = src_lo[c];
    }
  }

  // --- fp64-quantize A fragments in-register -------------------------------
  // Lane holds elems s*32+koff..+8 of its row; lanes {l&15 fixed, l>>4
  // varying} hold one 32-elem quant group -> amax via shfl_xor 16/32.
  bf16x8 ah[2], al[2];
  #pragma unroll
  for (int s = 0; s < 2; ++s) {
    float4 w0 = wr[s][0], w1 = wr[s][1];
    float wv[8] = {w0.x, w0.y, w0.z, w0.w, w1.x, w1.y, w1.z, w1.w};
    float a = 0.0f;
    #pragma unroll
    for (int j = 0; j < 8; ++j) a = fmaxf(a, fabsf(wv[j]));
    a = fmaxf(a, __shfl_xor(a, 16));
    a = fmaxf(a, __shfl_xor(a, 32));
    double sc = fmax((double)a, 1e-8) / 7.0;
    union { unsigned short s8[8]; bf16x8 b; } uh, ul;
    #pragma unroll
    for (int j = 0; j < 8; ++j) {
      unsigned short hi, lo;
      quant_elem(wv[j], sc, &hi, &lo);
      uh.s8[j] = hi;
      ul.s8[j] = lo;
    }
    ah[s] = uh.b;
    al[s] = ul.b;
  }

  __syncthreads();

  // --- MFMA: 4 n-frags x 2 k-steps x {hi*hi, hi*lo, lo*hi} -----------------
  f32x4 acc[4];
  #pragma unroll
  for (int nf = 0; nf < 4; ++nf) acc[nf] = (f32x4){0.f, 0.f, 0.f, 0.f};

  #pragma unroll
  for (int nf = 0; nf < 4; ++nf) {
    #pragma unroll
    for (int s = 0; s < 2; ++s) {
      const int boff = (nf * 16 + nlane) * LDS_STRIDE + s * 32 + koff;
      union { uint4 u; bf16x8 b; } bh, bl;
      bh.u = *(const uint4*)&bt_hi[boff];
      bl.u = *(const uint4*)&bt_lo[boff];
      acc[nf] = __builtin_amdgcn_mfma_f32_16x16x32_bf16(ah[s], bh.b, acc[nf], 0, 0, 0);
      acc[nf] = __builtin_amdgcn_mfma_f32_16x16x32_bf16(ah[s], bl.b, acc[nf], 0, 0, 0);
      acc[nf] = __builtin_amdgcn_mfma_f32_16x16x32_bf16(al[s], bh.b, acc[nf], 0, 0, 0);
    }
  }

  __syncthreads();   // done reading B planes; reuse smem for out-transpose

  // --- per-wave LDS transpose + coalesced nt stores ------------------------
  float* wp = ot + wave * 16 * OT_STRIDE;
  {
    const int r0 = (lane >> 4) << 2;         // 0,4,8,12
    #pragma unroll
    for (int nf = 0; nf < 4; ++nf) {
      #pragma unroll
      for (int i = 0; i < 4; ++i) {
        wp[(r0 + i) * OT_STRIDE + nlane + nf * 16] = acc[nf][i];
      }
    }
  }
  #pragma unroll
  for (int j = 0; j < 4; ++j) {
    const int row = j * 4 + (lane >> 4);     // 0..15
    f32x4 v = *(const f32x4*)&wp[row * OT_STRIDE + nlane * 4];
    // 16 lanes x 16B = one contiguous 256B row segment; 4 rows per inst
    __builtin_nontemporal_store(v,
        (f32x4*)&out[(size_t)(m0 + row) * D_DIM + n0 + nlane * 4]);
  }
}

extern "C" void kernel_launch(void* const* d_in, const int* in_sizes, int n_in,
                              void* d_out, int out_size, void* d_ws, size_t ws_size,
                              hipStream_t stream) {
  const float* U   = (const float*)d_in[0];
  const float* B   = (const float*)d_in[1];
  const int*   ids = (const int*)d_in[2];
  float* out = (float*)d_out;

  unsigned short* BqT_hi = (unsigned short*)d_ws;                       // 128 KB
  unsigned short* BqT_lo = BqT_hi + R_DIM * D_DIM;                      // 128 KB

  quantB_kernel<<<(R_DIM * D_DIM) / (256 * 4), 256, 0, stream>>>(B, BqT_hi, BqT_lo);
  gemm_kernel<<<(N_IDS / BM) * (D_DIM / BN), 256, 0, stream>>>(U, ids, BqT_hi, BqT_lo, out);
}

// Round 14
// 28.270 us; speedup vs baseline: 1.8405x; 1.1565x over previous
//
#include <hip/hip_runtime.h>

// QuantHotLowRank: out[n][d] = sum_r Uq[ids[n]][r] * Bq[r][d]
// K=200000, R=64, D=1024, N=16384, 4-bit groupwise fake-quant, group=32.
//
// SINGLE kernel, BM=128 x BN=128 (1024 blocks, 4/CU). Each block requants its
// own 128-col B-slice into LDS (R11 structure), but with the fp64 cost cut
// ~6x by a GUARDED quant path:
//   t32 = w * rcp32 (SP, rcp once/group, correctly rounded; |t|<=7 so abs
//   err <= ~1.3e-6). n = rintf(t32), UNLESS t32 is within 1e-4 of a
//   half-integer boundary (~4e-4 of elems) -> redo division in fp64.
//   q = n * scale_d always in fp64 (single mul) -> bit-identical to numpy's
//   fp64 fake-quant everywhere (decision provably equal outside the guard,
//   exact inside).
// A rows: gathered + guarded-quantized in-register (fragment-aligned, amax
// via shfl_xor 16/32). Split-bf16 MFMA (hi*hi + hi*lo + lo*hi, ~2^-18).
// LDS-transpose + coalesced 512B-segment nontemporal stores.
//
// Ledger: coop grid-sync 5.7x worse (R9); fp64 B-requant fusion -1.7us (R11,
// this round fixes its DP cost); zero-LDS VGPR32 -25us (R12); 8 blocks/CU
// -5.4us (R13); BM=128 / nt stores / LDS-transpose neutral (R10/R6/R4).

#define R_DIM 64
#define D_DIM 1024
#define N_IDS 16384

#define BM 128         // rows per tile (4 waves x 2 m-frags x 16)
#define BN 128         // cols per tile
#define LDS_STRIDE 72  // ushorts per B-LDS row: 64 + 8 pad
#define OT_STRIDE 132  // floats per out-LDS row: 128 + 4 pad

typedef __attribute__((ext_vector_type(8))) __bf16 bf16x8;
typedef __attribute__((ext_vector_type(4))) float f32x4;

__device__ inline unsigned short f32_to_bf16_rne(float f) {
  union { float f; unsigned int u; } c; c.f = f;
  unsigned int u = c.u;
  u += 0x7fffu + ((u >> 16) & 1u);   // round-to-nearest-even (finite inputs only)
  return (unsigned short)(u >> 16);
}

__device__ inline float bf16_bits_to_f32(unsigned short h) {
  union { unsigned int u; float f; } c; c.u = ((unsigned int)h) << 16;
  return c.f;
}

// Guarded fake-quant: SP fast path for the rint decision, fp64 only within
// 1e-4 of a half-integer boundary; q = n*scale_d in fp64 (bit-exact to np).
__device__ inline void quant_elem_g(float w, float rcp32, double scale_d,
                                    unsigned short* hi, unsigned short* lo) {
  float t32 = w * rcp32;
  float n32 = rintf(t32);
  double n;
  if (__builtin_expect(fabsf(fabsf(t32 - n32) - 0.5f) < 1e-4f, 0)) {
    n = rint((double)w / scale_d);           // exact decision at the boundary
  } else {
    n = (double)n32;
  }
  n = fmin(fmax(n, -7.0), 7.0);
  float qf = (float)(n * scale_d);
  unsigned short h = f32_to_bf16_rne(qf);
  *hi = h;
  *lo = f32_to_bf16_rne(qf - bf16_bits_to_f32(h));
}

// ---------------- fused kernel: B-quant->LDS, A-quant->regs, MFMA, store ----
__global__ __launch_bounds__(256, 4) void gemm_kernel(
    const float* __restrict__ U, const float* __restrict__ B,
    const int* __restrict__ ids, float* __restrict__ out) {
  // B planes (2 x 18KB) overlaid with the out-transpose buffer (33KB).
  // 36864B -> 4 blocks/CU.
  __shared__ char smem[2 * BN * LDS_STRIDE * 2];
  unsigned short* bt_hi = (unsigned short*)smem;
  unsigned short* bt_lo = bt_hi + BN * LDS_STRIDE;
  float* ot = (float*)smem;

  const int tid  = threadIdx.x;
  const int lane = tid & 63;
  const int wave = tid >> 6;
  const int bx   = blockIdx.x;
  const int mb   = bx & 127;   // same-U-rows blocks are 128 apart == same XCD
  const int nb   = bx >> 7;    // 8 col-slices
  const int n0   = nb * BN;
  const int m0b  = mb * BM;
  const int koff  = (lane >> 4) * 8;         // k-chunk of 8 within the 32-group
  const int nlane = lane & 15;

  // --- A gather loads FIRST (in flight under the B-quant work) -------------
  const float* urow0 = U + (size_t)ids[m0b + wave * 16 + nlane] * R_DIM;
  const float* urow1 = U + (size_t)ids[m0b + 64 + wave * 16 + nlane] * R_DIM;
  float4 wr[2][2][2];
  #pragma unroll
  for (int s = 0; s < 2; ++s) {
    wr[0][s][0] = *(const float4*)(urow0 + s * 32 + koff);
    wr[0][s][1] = *(const float4*)(urow0 + s * 32 + koff + 4);
    wr[1][s][0] = *(const float4*)(urow1 + s * 32 + koff);
    wr[1][s][1] = *(const float4*)(urow1 + s * 32 + koff + 4);
  }

  // --- requantize this block's B-slice straight into LDS (guarded path) ----
  // Thread t -> row r = t>>2, quant-group g = t&3 (cols n0+g*32..+32 of row
  // r = exactly one group): amax thread-local, decisions == numpy's fp64.
  {
    const int r = tid >> 2, g = tid & 3;
    const float* bp = B + (size_t)r * D_DIM + n0 + g * 32;
    float4 bv[8];
    #pragma unroll
    for (int q = 0; q < 8; ++q) bv[q] = *(const float4*)(bp + q * 4);
    float a = 0.0f;
    #pragma unroll
    for (int q = 0; q < 8; ++q)
      a = fmaxf(a, fmaxf(fmaxf(fabsf(bv[q].x), fabsf(bv[q].y)),
                         fmaxf(fabsf(bv[q].z), fabsf(bv[q].w))));
    const double sc = fmax((double)a, 1e-8) / 7.0;   // one DP div per group
    const float rcp = 1.0f / (float)sc;              // correctly-rounded SP
    #pragma unroll
    for (int q = 0; q < 8; ++q) {
      float wv[4] = {bv[q].x, bv[q].y, bv[q].z, bv[q].w};
      #pragma unroll
      for (int j = 0; j < 4; ++j) {
        unsigned short hi, lo;
        quant_elem_g(wv[j], rcp, sc, &hi, &lo);
        const int c = g * 32 + q * 4 + j;            // local col 0..127
        bt_hi[c * LDS_STRIDE + r] = hi;
        bt_lo[c * LDS_STRIDE + r] = lo;
      }
    }
  }

  // --- guarded-quantize A fragments in-register ----------------------------
  // Lane holds elems s*32+koff..+8 of its row; lanes {l&15 fixed, l>>4
  // varying} hold one 32-elem quant group -> amax via shfl_xor 16/32.
  bf16x8 ah[2][2], al[2][2];
  #pragma unroll
  for (int mf = 0; mf < 2; ++mf) {
    #pragma unroll
    for (int s = 0; s < 2; ++s) {
      float4 w0 = wr[mf][s][0], w1 = wr[mf][s][1];
      float wv[8] = {w0.x, w0.y, w0.z, w0.w, w1.x, w1.y, w1.z, w1.w};
      float a = 0.0f;
      #pragma unroll
      for (int j = 0; j < 8; ++j) a = fmaxf(a, fabsf(wv[j]));
      a = fmaxf(a, __shfl_xor(a, 16));
      a = fmaxf(a, __shfl_xor(a, 32));
      const double sc = fmax((double)a, 1e-8) / 7.0;
      const float rcp = 1.0f / (float)sc;
      union { unsigned short s8[8]; bf16x8 b; } uh, ul;
      #pragma unroll
      for (int j = 0; j < 8; ++j) {
        unsigned short hi, lo;
        quant_elem_g(wv[j], rcp, sc, &hi, &lo);
        uh.s8[j] = hi;
        ul.s8[j] = lo;
      }
      ah[mf][s] = uh.b;
      al[mf][s] = ul.b;
    }
  }

  __syncthreads();   // B planes fully written

  // --- MFMA: 8 n-frags x 2 k-steps x 2 m-frags x {hi*hi, hi*lo, lo*hi} -----
  f32x4 acc[2][8];
  #pragma unroll
  for (int mf = 0; mf < 2; ++mf)
    #pragma unroll
    for (int nf = 0; nf < 8; ++nf) acc[mf][nf] = (f32x4){0.f, 0.f, 0.f, 0.f};

  #pragma unroll
  for (int nf = 0; nf < 8; ++nf) {
    #pragma unroll
    for (int s = 0; s < 2; ++s) {
      const int boff = (nf * 16 + nlane) * LDS_STRIDE + s * 32 + koff;
      union { uint4 u; bf16x8 b; } bh, bl;
      bh.u = *(const uint4*)&bt_hi[boff];
      bl.u = *(const uint4*)&bt_lo[boff];
      #pragma unroll
      for (int mf = 0; mf < 2; ++mf) {
        acc[mf][nf] = __builtin_amdgcn_mfma_f32_16x16x32_bf16(ah[mf][s], bh.b, acc[mf][nf], 0, 0, 0);
        acc[mf][nf] = __builtin_amdgcn_mfma_f32_16x16x32_bf16(ah[mf][s], bl.b, acc[mf][nf], 0, 0, 0);
        acc[mf][nf] = __builtin_amdgcn_mfma_f32_16x16x32_bf16(al[mf][s], bh.b, acc[mf][nf], 0, 0, 0);
      }
    }
  }

  __syncthreads();   // done reading B planes; reuse smem for out-transpose

  // --- per-wave LDS transpose + coalesced nt stores, one round per m-frag ---
  float* wp = ot + wave * 16 * OT_STRIDE;
  #pragma unroll
  for (int mf = 0; mf < 2; ++mf) {
    const int r0 = (lane >> 4) << 2;         // 0,4,8,12
    #pragma unroll
    for (int nf = 0; nf < 8; ++nf) {
      #pragma unroll
      for (int i = 0; i < 4; ++i) {
        wp[(r0 + i) * OT_STRIDE + nlane + nf * 16] = acc[mf][nf][i];
      }
    }
    const int orow0 = m0b + mf * 64 + wave * 16;
    #pragma unroll
    for (int j = 0; j < 8; ++j) {
      const int row = j * 2 + (lane >> 5);   // 0..15
      f32x4 v = *(const f32x4*)&wp[row * OT_STRIDE + (lane & 31) * 4];
      // 32 lanes x 16B = one contiguous 512B row segment; nt write-once stream
      __builtin_nontemporal_store(v,
          (f32x4*)&out[(size_t)(orow0 + row) * D_DIM + n0 + (lane & 31) * 4]);
    }
  }
}

extern "C" void kernel_launch(void* const* d_in, const int* in_sizes, int n_in,
                              void* d_out, int out_size, void* d_ws, size_t ws_size,
                              hipStream_t stream) {
  const float* U   = (const float*)d_in[0];
  const float* B   = (const float*)d_in[1];
  const int*   ids = (const int*)d_in[2];
  float* out = (float*)d_out;

  gemm_kernel<<<(N_IDS / BM) * (D_DIM / BN), 256, 0, stream>>>(U, B, ids, out);
}